// Round 7
// baseline (171.047 us; speedup 1.0000x reference)
//
#include <hip/hip_runtime.h>
#include <math.h>

#define B_DIM 8
#define S_DIM 4096
#define D_DIM 1024
#define N_DIM 16
#define ROWS (B_DIM * S_DIM)          // 32768

#define CHUNK_L 32
#define WARM 64
#define STEPS (CHUNK_L + WARM)        // 96 sequential steps per chain
#define NCHAIN (B_DIM * (S_DIM / CHUNK_L))   // 1024 chains

#define XB_BLOCKS 512                 // 128 row-tiles x 4 k-quarters
#define CW_BLOCKS ((N_DIM * D_DIM) / 256)  // 64
#define XROWS 256                     // rows per xb block
#define KQ 256                        // k per quarter
#define CK 32                         // k per LDS chunk
#define PAD 36                        // 32 + 4: rotates bank windows per row

// ---------------------------------------------------------------------------
// Kernel 1 (fused):
//  blocks [0, XB_BLOCKS): partial xb GEMM. Thread owns ONE row x all 16 n
//  (16 VGPR acc). B[k][*] reads are wave-uniform -> compiler scalarizes to
//  s_load (SMEM path) — ZERO DS traffic for B. x staged per-32k chunk into
//  LDS [256][36] (pad-4 spreads banks; all reads/writes ds_*_b128 at the
//  wave64 floor), chunk c+1 prefetched into regs during compute of c (T14).
//  Split-K 4-ways for occupancy (2.25 blocks/CU, 9 waves/CU); partials
//  summed by k_red.
//  blocks [XB_BLOCKS, +CW_BLOCKS): CW[n][d] = sum_k C[n][k]*W[d][k].
// ---------------------------------------------------------------------------
__global__ __launch_bounds__(256) void k_xbcw(const float* __restrict__ x,
                                              const float* __restrict__ Bm,
                                              float* __restrict__ parts,
                                              const float* __restrict__ C,
                                              const float* __restrict__ W,
                                              float* __restrict__ CW) {
    const int t = threadIdx.x;
    if (blockIdx.x >= XB_BLOCKS) {
        // ---- CW part (round-1 proven) ----
        int u = (blockIdx.x - XB_BLOCKS) * 256 + t;
        int d = u >> 4;
        int n = u & 15;
        const float* crow = C + n * D_DIM;
        const float* wrow = W + (size_t)d * D_DIM;
        float acc = 0.f;
#pragma unroll 4
        for (int k = 0; k < D_DIM; k += 4) {
            float4 c4 = *(const float4*)(crow + k);
            float4 w4 = *(const float4*)(wrow + k);
            acc = fmaf(c4.x, w4.x, acc);
            acc = fmaf(c4.y, w4.y, acc);
            acc = fmaf(c4.z, w4.z, acc);
            acc = fmaf(c4.w, w4.w, acc);
        }
        CW[n * D_DIM + d] = acc;
        return;
    }
    // ---- xb partial ----
    __shared__ float xs[XROWS * PAD];          // 36.9 KB
    const int rt = blockIdx.x >> 2;            // row tile 0..127
    const int kq = blockIdx.x & 3;             // k-quarter 0..3
    const int row0 = rt * XROWS;
    const int kq0 = kq * KQ;
    const float* xbase = x + (size_t)row0 * D_DIM + kq0;

    float acc[16];
#pragma unroll
    for (int n = 0; n < 16; ++n) acc[n] = 0.f;

    float4 pf[8];
    // prefetch chunk 0: 2048 float4, 8/thread; 8 lanes cover 128B runs
#pragma unroll
    for (int p = 0; p < 8; ++p) {
        int fid = p * 256 + t;
        int r = fid >> 3;
        int q = fid & 7;
        pf[p] = *(const float4*)(xbase + (size_t)r * D_DIM + q * 4);
    }

    for (int c = 0; c < 8; ++c) {
        __syncthreads();                       // protect prev chunk's reads
#pragma unroll
        for (int p = 0; p < 8; ++p) {
            int fid = p * 256 + t;
            int r = fid >> 3;
            int q = fid & 7;
            *(float4*)(xs + r * PAD + q * 4) = pf[p];
        }
        __syncthreads();
        if (c < 7) {                           // prefetch next chunk
#pragma unroll
            for (int p = 0; p < 8; ++p) {
                int fid = p * 256 + t;
                int r = fid >> 3;
                int q = fid & 7;
                pf[p] = *(const float4*)(xbase + (size_t)r * D_DIM +
                                         (c + 1) * CK + q * 4);
            }
        }
        // compute: row == t; B rows via wave-uniform (scalar) loads
        const float* bk = Bm + (size_t)(kq0 + c * CK) * N_DIM;
#pragma unroll
        for (int j = 0; j < 8; ++j) {
            float4 xv = *(const float4*)(xs + t * PAD + j * 4);
            const float* b0 = bk + (j * 4 + 0) * N_DIM;
            const float* b1 = bk + (j * 4 + 1) * N_DIM;
            const float* b2 = bk + (j * 4 + 2) * N_DIM;
            const float* b3 = bk + (j * 4 + 3) * N_DIM;
#pragma unroll
            for (int n = 0; n < 16; ++n) {
                float a = acc[n];
                a = fmaf(xv.x, b0[n], a);
                a = fmaf(xv.y, b1[n], a);
                a = fmaf(xv.z, b2[n], a);
                a = fmaf(xv.w, b3[n], a);
                acc[n] = a;
            }
        }
    }
    float* op = parts + ((size_t)kq * ROWS + row0 + t) * N_DIM;
#pragma unroll
    for (int j = 0; j < 4; ++j) {
        float4 v = {acc[j * 4 + 0], acc[j * 4 + 1],
                    acc[j * 4 + 2], acc[j * 4 + 3]};
        *(float4*)(op + j * 4) = v;
    }
}

// ---------------------------------------------------------------------------
// Kernel 1b: xb = sum of 4 k-quarter partials (pairwise; L2-resident, ~2 us)
// ---------------------------------------------------------------------------
__global__ __launch_bounds__(256) void k_red(const float* __restrict__ parts,
                                             float* __restrict__ xb) {
    int i = (blockIdx.x * 256 + threadIdx.x) * 4;
    const size_t Q = (size_t)ROWS * N_DIM;
    float4 a = *(const float4*)(parts + i);
    float4 b = *(const float4*)(parts + Q + i);
    float4 c = *(const float4*)(parts + 2 * Q + i);
    float4 d = *(const float4*)(parts + 3 * Q + i);
    float4 s = {(a.x + b.x) + (c.x + d.x), (a.y + b.y) + (c.y + d.y),
                (a.z + b.z) + (c.z + d.z), (a.w + b.w) + (c.w + d.w)};
    *(float4*)(xb + i) = s;
}

// ---------------------------------------------------------------------------
// Kernel 2: chunked scan (round-6 proven, UNCHANGED)
// ---------------------------------------------------------------------------
__global__ __launch_bounds__(64) void k_scan(const float* __restrict__ xb,
                                             const float* __restrict__ A,
                                             float* __restrict__ hs) {
    const int tid = threadIdx.x;           // 0..63
    const int n = tid & 15;
    const int base4 = (tid & 48) * 4;

    const int chain = blockIdx.x * 4 + (tid >> 4);   // 0..1023
    const int b = chain >> 7;
    const int chunk = chain & 127;
    const int t0 = chunk * CHUNK_L - WARM;

    float Ar[16];
#pragma unroll
    for (int m4 = 0; m4 < 16; m4 += 4) {
        float4 v = *(const float4*)(A + n * 16 + m4);
        Ar[m4 + 0] = v.x; Ar[m4 + 1] = v.y; Ar[m4 + 2] = v.z; Ar[m4 + 3] = v.w;
    }

    const float* xp = xb + (size_t)b * S_DIM * N_DIM + n;
    float* hp = hs + (size_t)b * S_DIM * N_DIM + n;

    float ring[8];
#pragma unroll
    for (int i = 0; i < 8; ++i) {
        int tt = t0 + i;
        ring[i] = (tt >= 0) ? xp[(size_t)tt * N_DIM] : 0.f;
    }

    float h = 0.f;
    for (int tr0 = 0; tr0 < STEPS; tr0 += 8) {
#pragma unroll
        for (int j = 0; j < 8; ++j) {
            const int tr = tr0 + j;
            const float xv = ring[j];
            const int hbits = __float_as_int(h);
            int hm[16];
#pragma unroll
            for (int m = 0; m < 16; ++m)
                hm[m] = __builtin_amdgcn_ds_bpermute(base4 + m * 4, hbits);
            float acc0 = xv, acc1 = 0.f;
#pragma unroll
            for (int m = 0; m < 8; ++m) {
                acc0 = fmaf(Ar[m], __int_as_float(hm[m]), acc0);
                acc1 = fmaf(Ar[m + 8], __int_as_float(hm[m + 8]), acc1);
            }
            float g = acc0 + acc1;
            float ax = fabsf(g);
            float e = __expf(2.f * ax);
            float tv = 1.f - 2.f / (e + 1.f);
            h = (g < 0.f) ? -tv : tv;
            if (tr >= WARM)
                hp[(size_t)(t0 + tr) * N_DIM] = h;
            int tt = t0 + tr + 8;
            if (tr + 8 < STEPS)
                ring[j] = (tt >= 0) ? xp[(size_t)tt * N_DIM] : 0.f;
        }
    }
}

// ---------------------------------------------------------------------------
// Kernel 3: out[r][d] = sum_n hs[r][n] * CW[n][d] + bias[d]  (round-1 proven)
// ---------------------------------------------------------------------------
__global__ __launch_bounds__(256) void k_out(const float* __restrict__ hs,
                                             const float* __restrict__ CW,
                                             const float* __restrict__ bias,
                                             float* __restrict__ out) {
    const int t = threadIdx.x;
    const int d0 = t * 4;
    const int row0 = blockIdx.x * 32;
    float4 cw[16];
#pragma unroll
    for (int nn = 0; nn < 16; ++nn)
        cw[nn] = *(const float4*)(CW + nn * D_DIM + d0);
    float4 b4 = *(const float4*)(bias + d0);

    for (int r = row0; r < row0 + 32; ++r) {
        const float4* hp = (const float4*)(hs + (size_t)r * N_DIM);
        float4 h0 = hp[0], h1 = hp[1], h2 = hp[2], h3 = hp[3];
        float hv[16] = {h0.x, h0.y, h0.z, h0.w, h1.x, h1.y, h1.z, h1.w,
                        h2.x, h2.y, h2.z, h2.w, h3.x, h3.y, h3.z, h3.w};
        float4 acc = b4;
#pragma unroll
        for (int nn = 0; nn < 16; ++nn) {
            acc.x = fmaf(hv[nn], cw[nn].x, acc.x);
            acc.y = fmaf(hv[nn], cw[nn].y, acc.y);
            acc.z = fmaf(hv[nn], cw[nn].z, acc.z);
            acc.w = fmaf(hv[nn], cw[nn].w, acc.w);
        }
        *(float4*)(out + (size_t)r * D_DIM + d0) = acc;
    }
}

// ---------------------------------------------------------------------------
extern "C" void kernel_launch(void* const* d_in, const int* in_sizes, int n_in,
                              void* d_out, int out_size, void* d_ws,
                              size_t ws_size, hipStream_t stream) {
    const float* x    = (const float*)d_in[0];   // [8,4096,1024]
    const float* A    = (const float*)d_in[1];   // [16,16]
    const float* Bm   = (const float*)d_in[2];   // [1024,16]
    const float* C    = (const float*)d_in[3];   // [16,1024]
    const float* W    = (const float*)d_in[4];   // [1024,1024]
    const float* bias = (const float*)d_in[5];   // [1024]
    float* out = (float*)d_out;

    float* ws    = (float*)d_ws;
    float* xb    = ws;                           // 524288 floats
    float* hs    = ws + 524288;                  // 524288
    float* CW    = ws + 1048576;                 // 16384
    float* parts = ws + 1064960;                 // 4 * 524288 = 2097152

    k_xbcw<<<dim3(XB_BLOCKS + CW_BLOCKS), dim3(256), 0, stream>>>(
        x, Bm, parts, C, W, CW);
    k_red<<<dim3(ROWS * N_DIM / 1024), dim3(256), 0, stream>>>(parts, xb);
    k_scan<<<dim3(NCHAIN / 4), dim3(64), 0, stream>>>(xb, A, hs);
    k_out<<<dim3(ROWS / 32), dim3(256), 0, stream>>>(hs, CW, bias, out);
}